// Round 1
// baseline (836.065 us; speedup 1.0000x reference)
//
#include <hip/hip_runtime.h>

#define N_NODES 50000
#define N_EDGES 800000
#define HID 64
#define LAYERS 4

typedef unsigned short u16;
typedef __attribute__((ext_vector_type(8))) __bf16 bf16x8;
typedef __attribute__((ext_vector_type(8))) unsigned short u16x8;
typedef __attribute__((ext_vector_type(4))) float f32x4;

__device__ __forceinline__ u16 f2bf(float f) {
  unsigned u = __builtin_bit_cast(unsigned, f);
  u += 0x7fffu + ((u >> 16) & 1u);   // RNE
  return (u16)(u >> 16);
}
__device__ __forceinline__ float bf2f(u16 s) {
  return __builtin_bit_cast(float, ((unsigned)s) << 16);
}

// ---------------- weight prep: transpose to [feat][k], fold e-encoder into W1 ----
// W1x: [L][64][160] bf16  (k: 0-63 h_src, 64-127 h_dst, 128-130 Wv=We@W1c, 131-159 zero)
// b1x: [L][64] f32  (b1 + be@W1c)
// W2x: [L][64][64] bf16 ; M1x: [L][64][128] bf16 ; M2x: [L][64][64] bf16
__global__ void prep_kernel(const float* __restrict__ ew1, const float* __restrict__ eb1,
                            const float* __restrict__ ew2, const float* __restrict__ nw1,
                            const float* __restrict__ nw2,
                            const float* __restrict__ edge_enc_w, const float* __restrict__ edge_enc_b,
                            u16* W1x, float* b1x, u16* W2x, u16* M1x, u16* M2x) {
  int idx = blockIdx.x * 256 + threadIdx.x;
  const int szA = LAYERS * 64 * 160;
  const int szB = LAYERS * 64;
  const int szC = LAYERS * 64 * 64;
  const int szD = LAYERS * 64 * 128;
  const int szE = LAYERS * 64 * 64;
  if (idx < szA) {
    int l = idx / (64 * 160); int r = idx % (64 * 160);
    int f = r / 160; int k = r % 160;
    float v;
    if (k < 128) v = ew1[(l * 192 + k) * 64 + f];
    else if (k < 131) {
      int a = k - 128; float s = 0.f;
      for (int m = 0; m < 64; ++m) s += edge_enc_w[a * 64 + m] * ew1[(l * 192 + 128 + m) * 64 + f];
      v = s;
    } else v = 0.f;
    W1x[idx] = f2bf(v);
    return;
  }
  idx -= szA;
  if (idx < szB) {
    int l = idx / 64, f = idx % 64;
    float s = eb1[l * 64 + f];
    for (int m = 0; m < 64; ++m) s += edge_enc_b[m] * ew1[(l * 192 + 128 + m) * 64 + f];
    b1x[idx] = s;
    return;
  }
  idx -= szB;
  if (idx < szC) { int l = idx / 4096, r = idx % 4096, f = r / 64, k = r % 64;
    W2x[idx] = f2bf(ew2[(l * 64 + k) * 64 + f]); return; }
  idx -= szC;
  if (idx < szD) { int l = idx / 8192, r = idx % 8192, f = r / 128, k = r % 128;
    M1x[idx] = f2bf(nw1[(l * 128 + k) * 64 + f]); return; }
  idx -= szD;
  if (idx < szE) { int l = idx / 4096, r = idx % 4096, f = r / 64, k = r % 64;
    M2x[idx] = f2bf(nw2[(l * 64 + k) * 64 + f]); return; }
}

// ---------------- encoder: h = nf @ enc_w + enc_b  (bf16 out) ----------------
__global__ __launch_bounds__(256) void encode_kernel(const float* __restrict__ nf,
                                                     const float* __restrict__ enc_w,
                                                     const float* __restrict__ enc_b,
                                                     u16* __restrict__ h) {
  int idx = blockIdx.x * 256 + threadIdx.x;
  if (idx >= N_NODES * HID) return;
  int n = idx >> 6, j = idx & 63;
  float s = enc_b[j]
          + nf[n * 3 + 0] * enc_w[j]
          + nf[n * 3 + 1] * enc_w[64 + j]
          + nf[n * 3 + 2] * enc_w[128 + j];
  h[idx] = f2bf(s);
}

// ---------------- edge MLP + scatter-add, one 64-edge tile per block ----------
__global__ __launch_bounds__(256) void edge_kernel(
    const u16* __restrict__ h, const int* __restrict__ ei,
    const float* __restrict__ pos,
    const u16* __restrict__ W1x, const float* __restrict__ b1x,
    const u16* __restrict__ W2x, const float* __restrict__ eb2,
    float* __restrict__ agg, int layer) {
  __shared__ u16 Xs[64 * 168];   // [edge][160 k] pad->168
  __shared__ u16 Hs[64 * 72];    // hidden [edge][64] pad->72
  __shared__ int sDst[64];
  const int* srcA = ei;
  const int* dstA = ei + N_EDGES;
  int t = threadIdx.x;
  int lane = t & 63, wv = t >> 6;
  int n16 = lane & 15, quad = lane >> 4;
  int F = wv * 16;

  // preload B-fragments (weights) into registers: B[k=quad*8+j][n=lane&15]
  bf16x8 B1[5], B2[2];
  {
    const u16* p = W1x + (size_t)(layer * 64 + F + n16) * 160 + quad * 8;
#pragma unroll
    for (int ks = 0; ks < 5; ++ks) B1[ks] = __builtin_bit_cast(bf16x8, *(const u16x8*)(p + ks * 32));
    const u16* q = W2x + (size_t)(layer * 64 + F + n16) * 64 + quad * 8;
#pragma unroll
    for (int ks = 0; ks < 2; ++ks) B2[ks] = __builtin_bit_cast(bf16x8, *(const u16x8*)(q + ks * 32));
  }
  float bias1 = b1x[layer * 64 + F + n16];
  float bias2 = eb2[layer * 64 + F + n16];

  int e0 = blockIdx.x * 64;
  {
    int e = t >> 2, part = t & 3;          // 64 edges x 4 threads; part covers 16 u16
    int ge = e0 + e;
    int s = srcA[ge], d = dstA[ge];
    const u16* hs = h + (size_t)s * 64 + part * 16;
    const u16* hd = h + (size_t)d * 64 + part * 16;
    *(u16x8*)(Xs + e * 168 + part * 16)          = *(const u16x8*)(hs);
    *(u16x8*)(Xs + e * 168 + part * 16 + 8)      = *(const u16x8*)(hs + 8);
    *(u16x8*)(Xs + e * 168 + 64 + part * 16)     = *(const u16x8*)(hd);
    *(u16x8*)(Xs + e * 168 + 64 + part * 16 + 8) = *(const u16x8*)(hd + 8);
    u16x8 z = {0, 0, 0, 0, 0, 0, 0, 0};
    *(u16x8*)(Xs + e * 168 + 128 + part * 8) = z;  // zero k=128..159
    if (part == 0) {
      sDst[e] = d;
      float vx = pos[d * 3 + 0] - pos[s * 3 + 0];
      float vy = pos[d * 3 + 1] - pos[s * 3 + 1];
      float vz = pos[d * 3 + 2] - pos[s * 3 + 2];
      Xs[e * 168 + 128] = f2bf(vx);
      Xs[e * 168 + 129] = f2bf(vy);
      Xs[e * 168 + 130] = f2bf(vz);
    }
  }
  __syncthreads();

  // GEMM1: hidden[64e][64f] = X[64e][160] @ W1x^T ; wave handles 16 feats, 4 edge-tiles
  f32x4 acc[4];
#pragma unroll
  for (int m = 0; m < 4; ++m) acc[m] = (f32x4){0.f, 0.f, 0.f, 0.f};
#pragma unroll
  for (int m = 0; m < 4; ++m) {
    const u16* xp = Xs + (m * 16 + n16) * 168 + quad * 8;
#pragma unroll
    for (int ks = 0; ks < 5; ++ks) {
      bf16x8 a = __builtin_bit_cast(bf16x8, *(const u16x8*)(xp + ks * 32));
      acc[m] = __builtin_amdgcn_mfma_f32_16x16x32_bf16(a, B1[ks], acc[m], 0, 0, 0);
    }
  }
  // epilogue 1: bias + relu -> bf16 -> LDS (C layout: row=edge=(quad*4+r), col=feat)
#pragma unroll
  for (int m = 0; m < 4; ++m) {
#pragma unroll
    for (int r = 0; r < 4; ++r) {
      int e = m * 16 + quad * 4 + r;
      float v = acc[m][r] + bias1;
      v = v > 0.f ? v : 0.f;
      Hs[e * 72 + F + n16] = f2bf(v);
    }
  }
  __syncthreads();

  // GEMM2 + bias + fp32 atomic scatter into agg[dst]
#pragma unroll
  for (int m = 0; m < 4; ++m) {
    const u16* hp = Hs + (m * 16 + n16) * 72 + quad * 8;
    f32x4 c = (f32x4){0.f, 0.f, 0.f, 0.f};
#pragma unroll
    for (int ks = 0; ks < 2; ++ks) {
      bf16x8 a = __builtin_bit_cast(bf16x8, *(const u16x8*)(hp + ks * 32));
      c = __builtin_amdgcn_mfma_f32_16x16x32_bf16(a, B2[ks], c, 0, 0, 0);
    }
#pragma unroll
    for (int r = 0; r < 4; ++r) {
      int e = m * 16 + quad * 4 + r;
      atomicAdd(&agg[(size_t)sDst[e] * 64 + F + n16], c[r] + bias2);
    }
  }
}

// ---------------- node MLP: h2 = relu([h|agg]@M1+c1)@M2+c2 -------------------
__global__ __launch_bounds__(256) void node_kernel(
    const u16* __restrict__ h, const float* __restrict__ agg,
    const u16* __restrict__ M1x, const float* __restrict__ nb1,
    const u16* __restrict__ M2x, const float* __restrict__ nb2,
    u16* __restrict__ h2, int layer) {
  __shared__ u16 Xs[64 * 136];   // [node][128 k] pad->136
  __shared__ u16 Hs[64 * 72];
  int t = threadIdx.x;
  int lane = t & 63, wv = t >> 6;
  int n16 = lane & 15, quad = lane >> 4;
  int F = wv * 16;

  bf16x8 B1[4], B2[2];
  {
    const u16* p = M1x + (size_t)(layer * 64 + F + n16) * 128 + quad * 8;
#pragma unroll
    for (int ks = 0; ks < 4; ++ks) B1[ks] = __builtin_bit_cast(bf16x8, *(const u16x8*)(p + ks * 32));
    const u16* q = M2x + (size_t)(layer * 64 + F + n16) * 64 + quad * 8;
#pragma unroll
    for (int ks = 0; ks < 2; ++ks) B2[ks] = __builtin_bit_cast(bf16x8, *(const u16x8*)(q + ks * 32));
  }
  float bias1 = nb1[layer * 64 + F + n16];
  float bias2 = nb2[layer * 64 + F + n16];

  int n0 = blockIdx.x * 64;
  {
    int e = t >> 2, part = t & 3;
    int gn = n0 + e;
    u16* xr = Xs + e * 136;
    if (gn < N_NODES) {
      const u16* hp = h + (size_t)gn * 64 + part * 16;
      *(u16x8*)(xr + part * 16)     = *(const u16x8*)(hp);
      *(u16x8*)(xr + part * 16 + 8) = *(const u16x8*)(hp + 8);
      const float* ap = agg + (size_t)gn * 64 + part * 16;
      u16* w = xr + 64 + part * 16;
#pragma unroll
      for (int i = 0; i < 4; ++i) {
        float4 a = *(const float4*)(ap + i * 4);
        w[i * 4 + 0] = f2bf(a.x); w[i * 4 + 1] = f2bf(a.y);
        w[i * 4 + 2] = f2bf(a.z); w[i * 4 + 3] = f2bf(a.w);
      }
    } else {
      u16x8 z = {0, 0, 0, 0, 0, 0, 0, 0};
      *(u16x8*)(xr + part * 16)          = z;
      *(u16x8*)(xr + part * 16 + 8)      = z;
      *(u16x8*)(xr + 64 + part * 16)     = z;
      *(u16x8*)(xr + 64 + part * 16 + 8) = z;
    }
  }
  __syncthreads();

  f32x4 acc[4];
#pragma unroll
  for (int m = 0; m < 4; ++m) acc[m] = (f32x4){0.f, 0.f, 0.f, 0.f};
#pragma unroll
  for (int m = 0; m < 4; ++m) {
    const u16* xp = Xs + (m * 16 + n16) * 136 + quad * 8;
#pragma unroll
    for (int ks = 0; ks < 4; ++ks) {
      bf16x8 a = __builtin_bit_cast(bf16x8, *(const u16x8*)(xp + ks * 32));
      acc[m] = __builtin_amdgcn_mfma_f32_16x16x32_bf16(a, B1[ks], acc[m], 0, 0, 0);
    }
  }
#pragma unroll
  for (int m = 0; m < 4; ++m) {
#pragma unroll
    for (int r = 0; r < 4; ++r) {
      int e = m * 16 + quad * 4 + r;
      float v = acc[m][r] + bias1;
      v = v > 0.f ? v : 0.f;
      Hs[e * 72 + F + n16] = f2bf(v);
    }
  }
  __syncthreads();

#pragma unroll
  for (int m = 0; m < 4; ++m) {
    const u16* hp = Hs + (m * 16 + n16) * 72 + quad * 8;
    f32x4 c = (f32x4){0.f, 0.f, 0.f, 0.f};
#pragma unroll
    for (int ks = 0; ks < 2; ++ks) {
      bf16x8 a = __builtin_bit_cast(bf16x8, *(const u16x8*)(hp + ks * 32));
      c = __builtin_amdgcn_mfma_f32_16x16x32_bf16(a, B2[ks], c, 0, 0, 0);
    }
#pragma unroll
    for (int r = 0; r < 4; ++r) {
      int e = m * 16 + quad * 4 + r;
      int gn = n0 + e;
      if (gn < N_NODES) h2[(size_t)gn * 64 + F + n16] = f2bf(c[r] + bias2);
    }
  }
}

// ---------------- decoder: out = h @ dec_w + dec_b ---------------------------
__global__ __launch_bounds__(256) void decode_kernel(const u16* __restrict__ h,
                                                     const float* __restrict__ dec_w,
                                                     const float* __restrict__ dec_b,
                                                     float* __restrict__ out) {
  int t = threadIdx.x;
  int lane = t & 63, wv = t >> 6;
  int n = blockIdx.x * 4 + wv;
  float p = bf2f(h[(size_t)n * 64 + lane]) * dec_w[lane];
#pragma unroll
  for (int o = 32; o > 0; o >>= 1) p += __shfl_xor(p, o);
  if (lane == 0) out[n] = p + dec_b[0];
}

extern "C" void kernel_launch(void* const* d_in, const int* in_sizes, int n_in,
                              void* d_out, int out_size, void* d_ws, size_t ws_size,
                              hipStream_t stream) {
  const float* node_pos   = (const float*)d_in[0];
  const float* node_feat  = (const float*)d_in[1];
  const int*   edge_index = (const int*)d_in[2];
  const float* enc_w      = (const float*)d_in[3];
  const float* enc_b      = (const float*)d_in[4];
  const float* edge_enc_w = (const float*)d_in[5];
  const float* edge_enc_b = (const float*)d_in[6];
  const float* ew1        = (const float*)d_in[7];
  const float* eb1        = (const float*)d_in[8];
  const float* ew2        = (const float*)d_in[9];
  const float* eb2        = (const float*)d_in[10];
  const float* nw1        = (const float*)d_in[11];
  const float* nb1        = (const float*)d_in[12];
  const float* nw2        = (const float*)d_in[13];
  const float* nb2        = (const float*)d_in[14];
  const float* dec_w      = (const float*)d_in[15];
  const float* dec_b      = (const float*)d_in[16];
  float* out = (float*)d_out;

  char* ws = (char*)d_ws;
  size_t off = 0;
  u16*   hA  = (u16*)(ws + off);   off += (size_t)N_NODES * 64 * 2;   // 6,400,000
  u16*   hB  = (u16*)(ws + off);   off += (size_t)N_NODES * 64 * 2;   // 12,800,000
  float* agg = (float*)(ws + off); off += (size_t)N_NODES * 64 * 4;   // 25,600,000
  u16*   W1x = (u16*)(ws + off);   off += (size_t)LAYERS * 64 * 160 * 2;
  float* b1x = (float*)(ws + off); off += (size_t)LAYERS * 64 * 4;
  u16*   W2x = (u16*)(ws + off);   off += (size_t)LAYERS * 64 * 64 * 2;
  u16*   M1x = (u16*)(ws + off);   off += (size_t)LAYERS * 64 * 128 * 2;
  u16*   M2x = (u16*)(ws + off);   off += (size_t)LAYERS * 64 * 64 * 2;

  const int prepTotal = LAYERS * (64 * 160 + 64 + 64 * 64 + 64 * 128 + 64 * 64);
  prep_kernel<<<(prepTotal + 255) / 256, 256, 0, stream>>>(
      ew1, eb1, ew2, nw1, nw2, edge_enc_w, edge_enc_b, W1x, b1x, W2x, M1x, M2x);
  encode_kernel<<<(N_NODES * 64 + 255) / 256, 256, 0, stream>>>(node_feat, enc_w, enc_b, hA);

  u16* hcur = hA; u16* hnext = hB;
  for (int l = 0; l < LAYERS; ++l) {
    hipMemsetAsync(agg, 0, (size_t)N_NODES * 64 * 4, stream);
    edge_kernel<<<N_EDGES / 64, 256, 0, stream>>>(hcur, edge_index, node_pos,
                                                  W1x, b1x, W2x, eb2, agg, l);
    node_kernel<<<(N_NODES + 63) / 64, 256, 0, stream>>>(hcur, agg, M1x, nb1, M2x, nb2,
                                                         hnext, l);
    u16* tmp = hcur; hcur = hnext; hnext = tmp;
  }
  decode_kernel<<<N_NODES / 4, 256, 0, stream>>>(hcur, dec_w, dec_b, out);
}

// Round 2
// 577.205 us; speedup vs baseline: 1.4485x; 1.4485x over previous
//
#include <hip/hip_runtime.h>

#define N_NODES 50000
#define N_EDGES 800000
#define HID 64
#define LAYERS 4

typedef unsigned short u16;
typedef __attribute__((ext_vector_type(8))) __bf16 bf16x8;
typedef __attribute__((ext_vector_type(8))) unsigned short u16x8;
typedef __attribute__((ext_vector_type(4))) float f32x4;

__device__ __forceinline__ u16 f2bf(float f) {
  unsigned u = __builtin_bit_cast(unsigned, f);
  u += 0x7fffu + ((u >> 16) & 1u);   // RNE
  return (u16)(u >> 16);
}
__device__ __forceinline__ float bf2f(u16 s) {
  return __builtin_bit_cast(float, ((unsigned)s) << 16);
}

// ---------------- weight prep: transpose to [feat][k], fold e-encoder into W1 ----
__global__ void prep_kernel(const float* __restrict__ ew1, const float* __restrict__ eb1,
                            const float* __restrict__ ew2, const float* __restrict__ nw1,
                            const float* __restrict__ nw2,
                            const float* __restrict__ edge_enc_w, const float* __restrict__ edge_enc_b,
                            u16* W1x, float* b1x, u16* W2x, u16* M1x, u16* M2x) {
  int idx = blockIdx.x * 256 + threadIdx.x;
  const int szA = LAYERS * 64 * 160;
  const int szB = LAYERS * 64;
  const int szC = LAYERS * 64 * 64;
  const int szD = LAYERS * 64 * 128;
  const int szE = LAYERS * 64 * 64;
  if (idx < szA) {
    int l = idx / (64 * 160); int r = idx % (64 * 160);
    int f = r / 160; int k = r % 160;
    float v;
    if (k < 128) v = ew1[(l * 192 + k) * 64 + f];
    else if (k < 131) {
      int a = k - 128; float s = 0.f;
      for (int m = 0; m < 64; ++m) s += edge_enc_w[a * 64 + m] * ew1[(l * 192 + 128 + m) * 64 + f];
      v = s;
    } else v = 0.f;
    W1x[idx] = f2bf(v);
    return;
  }
  idx -= szA;
  if (idx < szB) {
    int l = idx / 64, f = idx % 64;
    float s = eb1[l * 64 + f];
    for (int m = 0; m < 64; ++m) s += edge_enc_b[m] * ew1[(l * 192 + 128 + m) * 64 + f];
    b1x[idx] = s;
    return;
  }
  idx -= szB;
  if (idx < szC) { int l = idx / 4096, r = idx % 4096, f = r / 64, k = r % 64;
    W2x[idx] = f2bf(ew2[(l * 64 + k) * 64 + f]); return; }
  idx -= szC;
  if (idx < szD) { int l = idx / 8192, r = idx % 8192, f = r / 128, k = r % 128;
    M1x[idx] = f2bf(nw1[(l * 128 + k) * 64 + f]); return; }
  idx -= szD;
  if (idx < szE) { int l = idx / 4096, r = idx % 4096, f = r / 64, k = r % 64;
    M2x[idx] = f2bf(nw2[(l * 64 + k) * 64 + f]); return; }
}

// ---------------- encoder ----------------------------------------------------
__global__ __launch_bounds__(256) void encode_kernel(const float* __restrict__ nf,
                                                     const float* __restrict__ enc_w,
                                                     const float* __restrict__ enc_b,
                                                     u16* __restrict__ h) {
  int idx = blockIdx.x * 256 + threadIdx.x;
  if (idx >= N_NODES * HID) return;
  int n = idx >> 6, j = idx & 63;
  float s = enc_b[j]
          + nf[n * 3 + 0] * enc_w[j]
          + nf[n * 3 + 1] * enc_w[64 + j]
          + nf[n * 3 + 2] * enc_w[128 + j];
  h[idx] = f2bf(s);
}

// ---------------- counting sort of edges by dst ------------------------------
__global__ __launch_bounds__(256) void hist_kernel(const int* __restrict__ dstA,
                                                   int* __restrict__ cnt) {
  int idx = blockIdx.x * 256 + threadIdx.x;
  if (idx < N_EDGES) atomicAdd(&cnt[dstA[idx]], 1);
}

__global__ __launch_bounds__(1024) void scan_kernel(const int* __restrict__ cnt,
                                                    int* __restrict__ offs) {
  __shared__ int sm[1024];
  __shared__ int carry;
  int tid = threadIdx.x;
  if (tid == 0) carry = 0;
  __syncthreads();
  for (int base = 0; base < N_NODES; base += 1024) {
    int v = (base + tid < N_NODES) ? cnt[base + tid] : 0;
    sm[tid] = v;
    __syncthreads();
    for (int off = 1; off < 1024; off <<= 1) {
      int u = (tid >= off) ? sm[tid - off] : 0;
      __syncthreads();
      sm[tid] += u;
      __syncthreads();
    }
    int incl = sm[tid];
    int c = carry;
    if (base + tid < N_NODES) offs[base + tid] = c + incl - v;
    __syncthreads();
    if (tid == 1023) carry = c + sm[1023];
    __syncthreads();
  }
}

__global__ __launch_bounds__(256) void scatter_kernel(const int* __restrict__ dstA,
                                                      const int* __restrict__ offs,
                                                      int* __restrict__ cursor,
                                                      int* __restrict__ perm) {
  int idx = blockIdx.x * 256 + threadIdx.x;
  if (idx >= N_EDGES) return;
  int d = dstA[idx];
  int p = atomicAdd(&cursor[d], 1);
  perm[offs[d] + p] = idx;
}

// ---------------- edge MLP + segmented reduction + scatter-add ---------------
__global__ __launch_bounds__(256) void edge_kernel(
    const u16* __restrict__ h, const int* __restrict__ ei,
    const int* __restrict__ perm,
    const float* __restrict__ pos,
    const u16* __restrict__ W1x, const float* __restrict__ b1x,
    const u16* __restrict__ W2x, const float* __restrict__ eb2,
    float* __restrict__ agg, int layer) {
  // Xs (bf16 input tile, 21504 B) is dead after GEMM1; Fs (fp32 GEMM2 out,
  // 64x66x4 = 16896 B) aliases it to keep LDS at ~31 KB (5 blocks/CU).
  __shared__ __align__(16) char XsRaw[64 * 168 * 2];
  __shared__ u16 Hs[64 * 72];    // hidden [edge][64] pad->72
  __shared__ int sDst[64];
  u16* Xs = (u16*)XsRaw;
  float* Fs = (float*)XsRaw;     // stride 66 floats -> 2-way (free) bank aliasing
  const int* srcA = ei;
  const int* dstA = ei + N_EDGES;
  int t = threadIdx.x;
  int lane = t & 63, wv = t >> 6;
  int n16 = lane & 15, quad = lane >> 4;
  int F = wv * 16;

  // preload B-fragments (weights) into registers: B[k=quad*8+j][n=lane&15]
  bf16x8 B1[5], B2[2];
  {
    const u16* p = W1x + (size_t)(layer * 64 + F + n16) * 160 + quad * 8;
#pragma unroll
    for (int ks = 0; ks < 5; ++ks) B1[ks] = __builtin_bit_cast(bf16x8, *(const u16x8*)(p + ks * 32));
    const u16* q = W2x + (size_t)(layer * 64 + F + n16) * 64 + quad * 8;
#pragma unroll
    for (int ks = 0; ks < 2; ++ks) B2[ks] = __builtin_bit_cast(bf16x8, *(const u16x8*)(q + ks * 32));
  }
  float bias1 = b1x[layer * 64 + F + n16];
  float bias2r = eb2[layer * 64 + lane];   // per-feature bias for the reduction phase

  int e0 = blockIdx.x * 64;
  {
    int e = t >> 2, part = t & 3;          // 64 edges x 4 threads; part covers 16 u16
    int ge = perm[e0 + e];                 // dst-sorted edge id
    int s = srcA[ge], d = dstA[ge];
    const u16* hs = h + (size_t)s * 64 + part * 16;
    const u16* hd = h + (size_t)d * 64 + part * 16;
    *(u16x8*)(Xs + e * 168 + part * 16)          = *(const u16x8*)(hs);
    *(u16x8*)(Xs + e * 168 + part * 16 + 8)      = *(const u16x8*)(hs + 8);
    *(u16x8*)(Xs + e * 168 + 64 + part * 16)     = *(const u16x8*)(hd);
    *(u16x8*)(Xs + e * 168 + 64 + part * 16 + 8) = *(const u16x8*)(hd + 8);
    u16x8 z = {0, 0, 0, 0, 0, 0, 0, 0};
    *(u16x8*)(Xs + e * 168 + 128 + part * 8) = z;  // zero k=128..159
    if (part == 0) {
      sDst[e] = d;
      float vx = pos[d * 3 + 0] - pos[s * 3 + 0];
      float vy = pos[d * 3 + 1] - pos[s * 3 + 1];
      float vz = pos[d * 3 + 2] - pos[s * 3 + 2];
      Xs[e * 168 + 128] = f2bf(vx);
      Xs[e * 168 + 129] = f2bf(vy);
      Xs[e * 168 + 130] = f2bf(vz);
    }
  }
  __syncthreads();

  // GEMM1: hidden[64e][64f] = X[64e][160] @ W1x^T
  f32x4 acc[4];
#pragma unroll
  for (int m = 0; m < 4; ++m) acc[m] = (f32x4){0.f, 0.f, 0.f, 0.f};
#pragma unroll
  for (int m = 0; m < 4; ++m) {
    const u16* xp = Xs + (m * 16 + n16) * 168 + quad * 8;
#pragma unroll
    for (int ks = 0; ks < 5; ++ks) {
      bf16x8 a = __builtin_bit_cast(bf16x8, *(const u16x8*)(xp + ks * 32));
      acc[m] = __builtin_amdgcn_mfma_f32_16x16x32_bf16(a, B1[ks], acc[m], 0, 0, 0);
    }
  }
  // epilogue 1: bias + relu -> bf16 -> LDS
#pragma unroll
  for (int m = 0; m < 4; ++m) {
#pragma unroll
    for (int r = 0; r < 4; ++r) {
      int e = m * 16 + quad * 4 + r;
      float v = acc[m][r] + bias1;
      v = v > 0.f ? v : 0.f;
      Hs[e * 72 + F + n16] = f2bf(v);
    }
  }
  __syncthreads();   // Hs ready; all Xs reads done -> Fs may overwrite

  // GEMM2 -> Fs (fp32, no bias here)
#pragma unroll
  for (int m = 0; m < 4; ++m) {
    const u16* hp = Hs + (m * 16 + n16) * 72 + quad * 8;
    f32x4 c = (f32x4){0.f, 0.f, 0.f, 0.f};
#pragma unroll
    for (int ks = 0; ks < 2; ++ks) {
      bf16x8 a = __builtin_bit_cast(bf16x8, *(const u16x8*)(hp + ks * 32));
      c = __builtin_amdgcn_mfma_f32_16x16x32_bf16(a, B2[ks], c, 0, 0, 0);
    }
#pragma unroll
    for (int r = 0; r < 4; ++r) {
      int e = m * 16 + quad * 4 + r;
      Fs[e * 66 + F + n16] = c[r];
    }
  }
  __syncthreads();

  // segmented reduction: wave wv scans edges [wv*16, wv*16+16), lane = feature.
  // dst comparisons are wave-uniform (sorted tile) -> no divergence.
  {
    float sum = 0.f;
    int cur = sDst[wv * 16];
#pragma unroll
    for (int i = 0; i < 16; ++i) {
      int e = wv * 16 + i;
      int d = sDst[e];
      if (d != cur) {
        atomicAdd(&agg[(size_t)cur * 64 + lane], sum);
        sum = 0.f;
        cur = d;
      }
      sum += Fs[e * 66 + lane] + bias2r;
    }
    atomicAdd(&agg[(size_t)cur * 64 + lane], sum);
  }
}

// ---------------- node MLP ---------------------------------------------------
__global__ __launch_bounds__(256) void node_kernel(
    const u16* __restrict__ h, const float* __restrict__ agg,
    const u16* __restrict__ M1x, const float* __restrict__ nb1,
    const u16* __restrict__ M2x, const float* __restrict__ nb2,
    u16* __restrict__ h2, int layer) {
  __shared__ u16 Xs[64 * 136];
  __shared__ u16 Hs[64 * 72];
  int t = threadIdx.x;
  int lane = t & 63, wv = t >> 6;
  int n16 = lane & 15, quad = lane >> 4;
  int F = wv * 16;

  bf16x8 B1[4], B2[2];
  {
    const u16* p = M1x + (size_t)(layer * 64 + F + n16) * 128 + quad * 8;
#pragma unroll
    for (int ks = 0; ks < 4; ++ks) B1[ks] = __builtin_bit_cast(bf16x8, *(const u16x8*)(p + ks * 32));
    const u16* q = M2x + (size_t)(layer * 64 + F + n16) * 64 + quad * 8;
#pragma unroll
    for (int ks = 0; ks < 2; ++ks) B2[ks] = __builtin_bit_cast(bf16x8, *(const u16x8*)(q + ks * 32));
  }
  float bias1 = nb1[layer * 64 + F + n16];
  float bias2 = nb2[layer * 64 + F + n16];

  int n0 = blockIdx.x * 64;
  {
    int e = t >> 2, part = t & 3;
    int gn = n0 + e;
    u16* xr = Xs + e * 136;
    if (gn < N_NODES) {
      const u16* hp = h + (size_t)gn * 64 + part * 16;
      *(u16x8*)(xr + part * 16)     = *(const u16x8*)(hp);
      *(u16x8*)(xr + part * 16 + 8) = *(const u16x8*)(hp + 8);
      const float* ap = agg + (size_t)gn * 64 + part * 16;
      u16* w = xr + 64 + part * 16;
#pragma unroll
      for (int i = 0; i < 4; ++i) {
        float4 a = *(const float4*)(ap + i * 4);
        w[i * 4 + 0] = f2bf(a.x); w[i * 4 + 1] = f2bf(a.y);
        w[i * 4 + 2] = f2bf(a.z); w[i * 4 + 3] = f2bf(a.w);
      }
    } else {
      u16x8 z = {0, 0, 0, 0, 0, 0, 0, 0};
      *(u16x8*)(xr + part * 16)          = z;
      *(u16x8*)(xr + part * 16 + 8)      = z;
      *(u16x8*)(xr + 64 + part * 16)     = z;
      *(u16x8*)(xr + 64 + part * 16 + 8) = z;
    }
  }
  __syncthreads();

  f32x4 acc[4];
#pragma unroll
  for (int m = 0; m < 4; ++m) acc[m] = (f32x4){0.f, 0.f, 0.f, 0.f};
#pragma unroll
  for (int m = 0; m < 4; ++m) {
    const u16* xp = Xs + (m * 16 + n16) * 136 + quad * 8;
#pragma unroll
    for (int ks = 0; ks < 4; ++ks) {
      bf16x8 a = __builtin_bit_cast(bf16x8, *(const u16x8*)(xp + ks * 32));
      acc[m] = __builtin_amdgcn_mfma_f32_16x16x32_bf16(a, B1[ks], acc[m], 0, 0, 0);
    }
  }
#pragma unroll
  for (int m = 0; m < 4; ++m) {
#pragma unroll
    for (int r = 0; r < 4; ++r) {
      int e = m * 16 + quad * 4 + r;
      float v = acc[m][r] + bias1;
      v = v > 0.f ? v : 0.f;
      Hs[e * 72 + F + n16] = f2bf(v);
    }
  }
  __syncthreads();

#pragma unroll
  for (int m = 0; m < 4; ++m) {
    const u16* hp = Hs + (m * 16 + n16) * 72 + quad * 8;
    f32x4 c = (f32x4){0.f, 0.f, 0.f, 0.f};
#pragma unroll
    for (int ks = 0; ks < 2; ++ks) {
      bf16x8 a = __builtin_bit_cast(bf16x8, *(const u16x8*)(hp + ks * 32));
      c = __builtin_amdgcn_mfma_f32_16x16x32_bf16(a, B2[ks], c, 0, 0, 0);
    }
#pragma unroll
    for (int r = 0; r < 4; ++r) {
      int e = m * 16 + quad * 4 + r;
      int gn = n0 + e;
      if (gn < N_NODES) h2[(size_t)gn * 64 + F + n16] = f2bf(c[r] + bias2);
    }
  }
}

// ---------------- decoder ----------------------------------------------------
__global__ __launch_bounds__(256) void decode_kernel(const u16* __restrict__ h,
                                                     const float* __restrict__ dec_w,
                                                     const float* __restrict__ dec_b,
                                                     float* __restrict__ out) {
  int t = threadIdx.x;
  int lane = t & 63, wv = t >> 6;
  int n = blockIdx.x * 4 + wv;
  float p = bf2f(h[(size_t)n * 64 + lane]) * dec_w[lane];
#pragma unroll
  for (int o = 32; o > 0; o >>= 1) p += __shfl_xor(p, o);
  if (lane == 0) out[n] = p + dec_b[0];
}

extern "C" void kernel_launch(void* const* d_in, const int* in_sizes, int n_in,
                              void* d_out, int out_size, void* d_ws, size_t ws_size,
                              hipStream_t stream) {
  const float* node_pos   = (const float*)d_in[0];
  const float* node_feat  = (const float*)d_in[1];
  const int*   edge_index = (const int*)d_in[2];
  const float* enc_w      = (const float*)d_in[3];
  const float* enc_b      = (const float*)d_in[4];
  const float* edge_enc_w = (const float*)d_in[5];
  const float* edge_enc_b = (const float*)d_in[6];
  const float* ew1        = (const float*)d_in[7];
  const float* eb1        = (const float*)d_in[8];
  const float* ew2        = (const float*)d_in[9];
  const float* eb2        = (const float*)d_in[10];
  const float* nw1        = (const float*)d_in[11];
  const float* nb1        = (const float*)d_in[12];
  const float* nw2        = (const float*)d_in[13];
  const float* nb2        = (const float*)d_in[14];
  const float* dec_w      = (const float*)d_in[15];
  const float* dec_b      = (const float*)d_in[16];
  float* out = (float*)d_out;

  char* ws = (char*)d_ws;
  size_t off = 0;
  u16*   hA  = (u16*)(ws + off);   off += (size_t)N_NODES * 64 * 2;
  u16*   hB  = (u16*)(ws + off);   off += (size_t)N_NODES * 64 * 2;
  float* agg = (float*)(ws + off); off += (size_t)N_NODES * 64 * 4;
  u16*   W1x = (u16*)(ws + off);   off += (size_t)LAYERS * 64 * 160 * 2;
  float* b1x = (float*)(ws + off); off += (size_t)LAYERS * 64 * 4;
  u16*   W2x = (u16*)(ws + off);   off += (size_t)LAYERS * 64 * 64 * 2;
  u16*   M1x = (u16*)(ws + off);   off += (size_t)LAYERS * 64 * 128 * 2;
  u16*   M2x = (u16*)(ws + off);   off += (size_t)LAYERS * 64 * 64 * 2;
  int*   cnt    = (int*)(ws + off); off += (size_t)N_NODES * 4;
  int*   offs   = (int*)(ws + off); off += (size_t)N_NODES * 4;
  int*   cursor = (int*)(ws + off); off += (size_t)N_NODES * 4;
  int*   perm   = (int*)(ws + off); off += (size_t)N_EDGES * 4;

  const int* dstA = edge_index + N_EDGES;

  const int prepTotal = LAYERS * (64 * 160 + 64 + 64 * 64 + 64 * 128 + 64 * 64);
  prep_kernel<<<(prepTotal + 255) / 256, 256, 0, stream>>>(
      ew1, eb1, ew2, nw1, nw2, edge_enc_w, edge_enc_b, W1x, b1x, W2x, M1x, M2x);
  encode_kernel<<<(N_NODES * 64 + 255) / 256, 256, 0, stream>>>(node_feat, enc_w, enc_b, hA);

  // one-time counting sort of edges by dst
  hipMemsetAsync(cnt, 0, (size_t)N_NODES * 4, stream);
  hipMemsetAsync(cursor, 0, (size_t)N_NODES * 4, stream);
  hist_kernel<<<(N_EDGES + 255) / 256, 256, 0, stream>>>(dstA, cnt);
  scan_kernel<<<1, 1024, 0, stream>>>(cnt, offs);
  scatter_kernel<<<(N_EDGES + 255) / 256, 256, 0, stream>>>(dstA, offs, cursor, perm);

  u16* hcur = hA; u16* hnext = hB;
  for (int l = 0; l < LAYERS; ++l) {
    hipMemsetAsync(agg, 0, (size_t)N_NODES * 64 * 4, stream);
    edge_kernel<<<N_EDGES / 64, 256, 0, stream>>>(hcur, edge_index, perm, node_pos,
                                                  W1x, b1x, W2x, eb2, agg, l);
    node_kernel<<<(N_NODES + 63) / 64, 256, 0, stream>>>(hcur, agg, M1x, nb1, M2x, nb2,
                                                         hnext, l);
    u16* tmp = hcur; hcur = hnext; hnext = tmp;
  }
  decode_kernel<<<N_NODES / 4, 256, 0, stream>>>(hcur, dec_w, dec_b, out);
}